// Round 10
// baseline (56.512 us; speedup 1.0000x reference)
//
#include <hip/hip_runtime.h>
#include <hip/hip_fp16.h>

#define NBATCH 64
#define NV 50000
#define NT 100000
#define FPB (NV * 3)          /* floats per batch = 150000 */
#define N4 (FPB / 4)          /* 37500 float4 per batch */

#define NTILES ((FPB + 63) / 64)   /* 2344 transpose tiles */
#define GBLOCKS 2048               /* gather blocks: 8/CU, 32 waves/CU */
#define GWAVES (GBLOCKS * 4)       /* 8192 gather waves, 1-2 groups each */
#define NGROUP (NT / 8)            /* 12500 groups of 8 triangles */
#define NCHUNK 16                  /* normalize blocks per batch */
#define CHUNK ((N4 + NCHUNK - 1) / NCHUNK)   /* 2344 float4 */

#define XF_BYTES ((size_t)FPB * NBATCH)      /* 9.6 MB fp8 planes */
#define WS_NEED (XF_BYTES + (size_t)NBATCH * GBLOCKS * 4 + 256)

typedef float f32x4 __attribute__((ext_vector_type(4)));
typedef float f32x2 __attribute__((ext_vector_type(2)));

/* f32 -> OCP e4m3fn with explicit round-to-nearest-even (via f16 RNE). */
__device__ __forceinline__ unsigned char enc_e4m3(float f) {
  const unsigned short h = __half_as_ushort(__float2half(f));  /* RNE */
  const unsigned s = (h >> 8) & 0x80;
  const int e = (h >> 10) & 0x1f;   /* f16 biased exp */
  const int m = h & 0x3ff;
  if (e == 0) return (unsigned char)s;           /* |v| < 2^-14 -> 0 */
  int E = e - 8;                                 /* e4m3 biased exp */
  if (E > 15) return (unsigned char)(s | 0x7e);  /* clamp to 448 */
  if (E <= 0) {                                  /* e4m3 subnormal (k * 2^-9) */
    const int mm = m | 0x400;
    const int shift = 8 - E;
    if (shift > 11) return (unsigned char)s;
    const int keep = mm >> shift;
    const int rem = mm & ((1 << shift) - 1);
    const int half = 1 << (shift - 1);
    const int k = keep + ((rem > half || (rem == half && (keep & 1))) ? 1 : 0);
    return (unsigned char)(s | k);               /* k==8 -> min normal, correct */
  }
  int keep = m >> 7;
  const int rem = m & 0x7f;
  keep += (rem > 0x40 || (rem == 0x40 && (keep & 1))) ? 1 : 0;
  if (keep == 8) { keep = 0; ++E; if (E > 15) return (unsigned char)(s | 0x7e); }
  unsigned code = s | ((unsigned)E << 3) | (unsigned)keep;
  if ((code & 0x7f) == 0x7f) code = s | 0x7e;    /* never emit NaN encoding */
  return (unsigned char)code;
}

/* ---- pass 1: x[b][f] -> fp8 planes xF[c][v][b]; (c,v) row = 64 B ---- */
__global__ __launch_bounds__(256) void transpose_kernel(
    const float* __restrict__ x, unsigned char* __restrict__ xF) {
  __shared__ float tile[64][65];
  const int tx = threadIdx.x & 63;
  const int ty = threadIdx.x >> 6;
  const int f0 = blockIdx.x * 64;
  const int fl = f0 + tx;
  #pragma unroll
  for (int i = ty; i < 64; i += 4)
    if (fl < FPB) tile[i][tx] = x[(size_t)i * FPB + fl];
  __syncthreads();
  #pragma unroll
  for (int i = ty; i < 64; i += 4) {
    const int f = f0 + i;
    if (f < FPB) {
      const int v = f / 3, c = f - 3 * v;
      xF[((size_t)c * NV + v) * 64 + tx] = enc_e4m3(tile[tx][i]);
    }
  }
}

/* ---- pass 2: 8-triangle packed fp8 gather; partials[b][blk] (f32) ----
   lane = (tri_sub = lane>>3, batch_octet = lane&7); per (slot,coord) one
   dwordx2 wave-load = 8 rows x 64 B. HW fp8 decode (exact). Per-wave acc in
   f32 (<=16 dets summed). */
__global__ __launch_bounds__(256) void gather_det8_kernel(
    const unsigned char* __restrict__ xF, const int* __restrict__ M,
    float* __restrict__ partials) {
  const int ty = threadIdx.x >> 6;
  const int tx = threadIdx.x & 63;
  const int w = blockIdx.x * 4 + ty;
  const int sub = tx >> 3;
  const int boct = tx & 7;
  const unsigned char* __restrict__ pX = xF;
  const unsigned char* __restrict__ pY = xF + (size_t)NV * 64;
  const unsigned char* __restrict__ pZ = xF + (size_t)2 * NV * 64;
  const size_t o = 8 * boct;            /* byte offset in 64B row, 8B aligned */
  __shared__ float red[4][64];

  float acc[8];
  #pragma unroll
  for (int j = 0; j < 8; ++j) acc[j] = 0.f;

  for (int g = w; g < NGROUP; g += GWAVES) {   /* 1 or 2 iterations */
    const int t = g * 8 + sub;
    const int i0 = M[3 * t + 0];
    const int i1 = M[3 * t + 1];
    const int i2 = M[3 * t + 2];
    const uint2 A0 = *(const uint2*)(pX + (size_t)i0 * 64 + o);
    const uint2 A1 = *(const uint2*)(pY + (size_t)i0 * 64 + o);
    const uint2 A2 = *(const uint2*)(pZ + (size_t)i0 * 64 + o);
    const uint2 B0 = *(const uint2*)(pX + (size_t)i1 * 64 + o);
    const uint2 B1 = *(const uint2*)(pY + (size_t)i1 * 64 + o);
    const uint2 B2 = *(const uint2*)(pZ + (size_t)i1 * 64 + o);
    const uint2 C0 = *(const uint2*)(pX + (size_t)i2 * 64 + o);
    const uint2 C1 = *(const uint2*)(pY + (size_t)i2 * 64 + o);
    const uint2 C2 = *(const uint2*)(pZ + (size_t)i2 * 64 + o);

    /* word-select and HI must be LITERALS for cvt_pk_f32_fp8 */
#define DET_PAIR(W, HI, J0)                                                   \
    {                                                                         \
      const f32x2 a0 = __builtin_amdgcn_cvt_pk_f32_fp8((int)A0.W, HI);        \
      const f32x2 a1 = __builtin_amdgcn_cvt_pk_f32_fp8((int)A1.W, HI);        \
      const f32x2 a2 = __builtin_amdgcn_cvt_pk_f32_fp8((int)A2.W, HI);        \
      const f32x2 b0 = __builtin_amdgcn_cvt_pk_f32_fp8((int)B0.W, HI);        \
      const f32x2 b1 = __builtin_amdgcn_cvt_pk_f32_fp8((int)B1.W, HI);        \
      const f32x2 b2 = __builtin_amdgcn_cvt_pk_f32_fp8((int)B2.W, HI);        \
      const f32x2 c0 = __builtin_amdgcn_cvt_pk_f32_fp8((int)C0.W, HI);        \
      const f32x2 c1 = __builtin_amdgcn_cvt_pk_f32_fp8((int)C1.W, HI);        \
      const f32x2 c2 = __builtin_amdgcn_cvt_pk_f32_fp8((int)C2.W, HI);        \
      _Pragma("unroll")                                                       \
      for (int q = 0; q < 2; ++q) {                                           \
        const float det = a0[q] * (b1[q] * c2[q] - b2[q] * c1[q]) +           \
                          a1[q] * (b2[q] * c0[q] - b0[q] * c2[q]) +           \
                          a2[q] * (b0[q] * c1[q] - b1[q] * c0[q]);            \
        acc[(J0) + q] += fabsf(det);                                          \
      }                                                                       \
    }
    DET_PAIR(x, false, 0)
    DET_PAIR(x, true,  2)
    DET_PAIR(y, false, 4)
    DET_PAIR(y, true,  6)
#undef DET_PAIR
  }
  /* reduce over tri-sub lanes (bits 3..5) — fixed order, deterministic */
  #pragma unroll
  for (int j = 0; j < 8; ++j) {
    acc[j] += __shfl_xor(acc[j], 8, 64);
    acc[j] += __shfl_xor(acc[j], 16, 64);
    acc[j] += __shfl_xor(acc[j], 32, 64);
  }
  if (sub == 0) {
    #pragma unroll
    for (int j = 0; j < 8; ++j) red[ty][boct * 8 + j] = acc[j];
  }
  __syncthreads();
  if (ty == 0) {
    const float s = ((red[0][tx] + red[1][tx]) + (red[2][tx] + red[3][tx]));
    partials[(size_t)tx * GBLOCKS + blockIdx.x] = s;
  }
}

/* ---- pass 3: fused finalize + normalize (double cross-block sum) ---- */
__global__ __launch_bounds__(256) void normfin_kernel(
    const float* __restrict__ x, const float* __restrict__ partials,
    float* __restrict__ out) {
  const int batch = blockIdx.x >> 4;
  const int chunk = blockIdx.x & (NCHUNK - 1);
  const int tid = threadIdx.x;
  const int tx = tid & 63;
  const int ty = tid >> 6;
  __shared__ double red[4];

  const float* __restrict__ pb = partials + (size_t)batch * GBLOCKS;
  double local = 0.0;
  #pragma unroll
  for (int k = 0; k < GBLOCKS / 256; ++k) local += (double)pb[tid + k * 256];
  #pragma unroll
  for (int off = 32; off > 0; off >>= 1) local += __shfl_down(local, off, 64);
  if (tx == 0) red[ty] = local;
  __syncthreads();
  const double vol = ((red[0] + red[1]) + (red[2] + red[3])) / 6.0;
  const float s = (float)(1.0 / cbrt(vol));

  const f32x4* __restrict__ xb = (const f32x4*)(x + (size_t)batch * FPB);
  f32x4* __restrict__ ob = (f32x4*)(out + (size_t)batch * FPB);
  const int i1 = min((chunk + 1) * CHUNK, N4);
  for (int i = chunk * CHUNK + tid; i < i1; i += 256) {
    f32x4 v = xb[i];
    v *= s;
    __builtin_nontemporal_store(v, &ob[i]);  /* out never re-read */
  }
}

/* ---------------- fallback (small ws): round-2 XCD-local path ------------ */

#define XCDS 8
#define SLOTS 256
#define BATCH_PER_XCD (NBATCH / XCDS)

__global__ __launch_bounds__(256) void vol_partial_kernel(
    const float* __restrict__ x, const int* __restrict__ M,
    double* __restrict__ partials) {
  const int L = blockIdx.x;
  const int xcd = L & (XCDS - 1);
  const int slot = L >> 3;
  __shared__ double lds[4];
  const int lane = threadIdx.x & 63;
  const int wave = threadIdx.x >> 6;
  for (int bi = 0; bi < BATCH_PER_XCD; ++bi) {
    const int b = xcd * BATCH_PER_XCD + bi;
    const float* __restrict__ xv = x + (size_t)b * FPB;
    double acc = 0.0;
    for (int t = slot * 256 + threadIdx.x; t < NT; t += SLOTS * 256) {
      const int i0 = M[3 * t + 0], i1 = M[3 * t + 1], i2 = M[3 * t + 2];
      const float a0 = xv[3 * i0], a1 = xv[3 * i0 + 1], a2 = xv[3 * i0 + 2];
      const float b0 = xv[3 * i1], b1 = xv[3 * i1 + 1], b2 = xv[3 * i1 + 2];
      const float c0 = xv[3 * i2], c1 = xv[3 * i2 + 1], c2 = xv[3 * i2 + 2];
      const float det = a0 * (b1 * c2 - b2 * c1) + a1 * (b2 * c0 - b0 * c2) +
                        a2 * (b0 * c1 - b1 * c0);
      acc += (double)fabsf(det);
    }
    #pragma unroll
    for (int off = 32; off > 0; off >>= 1) acc += __shfl_down(acc, off, 64);
    if (lane == 0) lds[wave] = acc;
    __syncthreads();
    if (threadIdx.x == 0)
      partials[(size_t)b * SLOTS + slot] = (lds[0] + lds[1]) + (lds[2] + lds[3]);
    __syncthreads();
  }
}

__global__ __launch_bounds__(256) void finalize_kernel(
    const double* __restrict__ partials, float* __restrict__ inv_scale) {
  const int b = blockIdx.x;
  double v = partials[(size_t)b * SLOTS + threadIdx.x];
  #pragma unroll
  for (int off = 32; off > 0; off >>= 1) v += __shfl_down(v, off, 64);
  __shared__ double lds[4];
  const int lane = threadIdx.x & 63;
  const int wave = threadIdx.x >> 6;
  if (lane == 0) lds[wave] = v;
  __syncthreads();
  if (threadIdx.x == 0) {
    const double vol = ((lds[0] + lds[1]) + (lds[2] + lds[3])) / 6.0;
    inv_scale[b] = (float)(1.0 / cbrt(vol));
  }
}

__global__ __launch_bounds__(256) void normalize_kernel(
    const float* __restrict__ x, const float* __restrict__ inv_scale,
    float* __restrict__ out) {
  const int b = blockIdx.y;
  const float s = inv_scale[b];
  const f32x4* __restrict__ xin =
      reinterpret_cast<const f32x4*>(x + (size_t)b * FPB);
  f32x4* __restrict__ o = reinterpret_cast<f32x4*>(out + (size_t)b * FPB);
  const int stride = blockDim.x * gridDim.x;
  for (int i = blockIdx.x * blockDim.x + threadIdx.x; i < N4; i += stride) {
    f32x4 v = xin[i];
    v *= s;
    __builtin_nontemporal_store(v, &o[i]);
  }
}

extern "C" void kernel_launch(void* const* d_in, const int* in_sizes, int n_in,
                              void* d_out, int out_size, void* d_ws, size_t ws_size,
                              hipStream_t stream) {
  const float* x = (const float*)d_in[0];
  const int* M = (const int*)d_in[1];
  float* out = (float*)d_out;

  if (ws_size >= WS_NEED) {
    unsigned char* xF = (unsigned char*)d_ws;
    float* partials = (float*)((char*)d_ws + XF_BYTES);
    transpose_kernel<<<NTILES, 256, 0, stream>>>(x, xF);
    gather_det8_kernel<<<GBLOCKS, 256, 0, stream>>>(xF, M, partials);
    normfin_kernel<<<NBATCH * NCHUNK, 256, 0, stream>>>(x, partials, out);
  } else {
    double* partials = (double*)d_ws;
    float* inv_scale = (float*)(partials + NBATCH * SLOTS);
    vol_partial_kernel<<<XCDS * SLOTS, 256, 0, stream>>>(x, M, partials);
    finalize_kernel<<<NBATCH, SLOTS, 0, stream>>>(partials, inv_scale);
    dim3 gridC(32, NBATCH);
    normalize_kernel<<<gridC, 256, 0, stream>>>(x, inv_scale, out);
  }
}

// Round 11
// 53.402 us; speedup vs baseline: 1.0583x; 1.0583x over previous
//
#include <hip/hip_runtime.h>
#include <hip/hip_fp16.h>

#define NBATCH 64
#define NV 50000
#define NT 100000
#define FPB (NV * 3)          /* floats per batch = 150000 */
#define N4 (FPB / 4)          /* 37500 float4 per batch */

#define NTILES ((FPB + 63) / 64)   /* 2344 transpose tiles */
#define GBLOCKS 2048               /* gather blocks: 8/CU, 32 waves/CU */
#define GWAVES (GBLOCKS * 4)       /* 8192 gather waves, 1-2 groups each */
#define NGROUP (NT / 8)            /* 12500 groups of 8 triangles */
#define NCHUNK 16                  /* normalize blocks per batch */
#define CHUNK ((N4 + NCHUNK - 1) / NCHUNK)   /* 2344 float4 */

#define XH_HALVES ((size_t)FPB * NBATCH)     /* 9.6e6 halves = 19.2 MB */
#define XH_BYTES (XH_HALVES * 2)
#define WS_NEED (XH_BYTES + (size_t)NBATCH * GBLOCKS * 8 + 256)

typedef float f32x4 __attribute__((ext_vector_type(4)));
typedef int i32x4 __attribute__((ext_vector_type(4)));

__device__ __forceinline__ float hext(const i32x4& v, int j) {
  const int word = v[j >> 1];
  const __half2 h = __builtin_bit_cast(__half2, word);
  return (j & 1) ? __high2float(h) : __low2float(h);
}

/* ---- pass 1: x[b][f] -> fp16 planes xH[c][v][b]; (c,v) row = one 128B line.
   Write side: lane l -> (hi = l>>5 selects f-row of the pair, j = l&31 packs
   batches 2j,2j+1 as __half2) -> one 256B-wide store instr per 2 rows. */
__global__ __launch_bounds__(256) void transpose_kernel(
    const float* __restrict__ x, __half* __restrict__ xH) {
  __shared__ float tile[64][65];
  const int tx = threadIdx.x & 63;
  const int ty = threadIdx.x >> 6;
  const int f0 = blockIdx.x * 64;
  const int fl = f0 + tx;
  #pragma unroll
  for (int i = ty; i < 64; i += 4)
    if (fl < FPB) tile[i][tx] = x[(size_t)i * FPB + fl];
  __syncthreads();
  const int hi = (threadIdx.x >> 5) & 1;
  const int j = threadIdx.x & 31;
  #pragma unroll
  for (int it = ty; it < 32; it += 4) {
    const int f = f0 + 2 * it + hi;
    if (f < FPB) {
      const int v = f / 3, c = f - 3 * v;
      const __half2 h2 = __halves2half2(__float2half(tile[2 * j][2 * it + hi]),
                                        __float2half(tile[2 * j + 1][2 * it + hi]));
      *reinterpret_cast<__half2*>(xH + ((size_t)c * NV + v) * 64 + 2 * j) = h2;
    }
  }
}

/* ---- pass 2: 8-triangle packed gather; block-reduced partials[b][blk] ----
   lane = (tri_sub = lane>>3, batch_octet = lane&7); one dwordx4 wave-load =
   8 full 128B rows. Per block: 4 waves LDS-reduced -> 64 doubles. */
__global__ __launch_bounds__(256) void gather_det8_kernel(
    const __half* __restrict__ xH, const int* __restrict__ M,
    double* __restrict__ partials) {
  const int ty = threadIdx.x >> 6;
  const int tx = threadIdx.x & 63;
  const int w = blockIdx.x * 4 + ty;
  const int sub = tx >> 3;
  const int boct = tx & 7;
  const __half* __restrict__ pX = xH;
  const __half* __restrict__ pY = xH + (size_t)NV * 64;
  const __half* __restrict__ pZ = xH + (size_t)2 * NV * 64;
  const size_t o = 8 * boct;
  __shared__ double red[4][64];

  double acc[8];
  #pragma unroll
  for (int j = 0; j < 8; ++j) acc[j] = 0.0;

  #pragma unroll 2
  for (int g = w; g < NGROUP; g += GWAVES) {   /* 1 or 2 iterations */
    const int t = g * 8 + sub;
    const int i0 = M[3 * t + 0];
    const int i1 = M[3 * t + 1];
    const int i2 = M[3 * t + 2];
    const i32x4 A0 = *(const i32x4*)(pX + (size_t)i0 * 64 + o);
    const i32x4 A1 = *(const i32x4*)(pY + (size_t)i0 * 64 + o);
    const i32x4 A2 = *(const i32x4*)(pZ + (size_t)i0 * 64 + o);
    const i32x4 B0 = *(const i32x4*)(pX + (size_t)i1 * 64 + o);
    const i32x4 B1 = *(const i32x4*)(pY + (size_t)i1 * 64 + o);
    const i32x4 B2 = *(const i32x4*)(pZ + (size_t)i1 * 64 + o);
    const i32x4 C0 = *(const i32x4*)(pX + (size_t)i2 * 64 + o);
    const i32x4 C1 = *(const i32x4*)(pY + (size_t)i2 * 64 + o);
    const i32x4 C2 = *(const i32x4*)(pZ + (size_t)i2 * 64 + o);
    #pragma unroll
    for (int j = 0; j < 8; ++j) {
      const float a0 = hext(A0, j), a1 = hext(A1, j), a2 = hext(A2, j);
      const float b0 = hext(B0, j), b1 = hext(B1, j), b2 = hext(B2, j);
      const float c0 = hext(C0, j), c1 = hext(C1, j), c2 = hext(C2, j);
      const float det = a0 * (b1 * c2 - b2 * c1) +
                        a1 * (b2 * c0 - b0 * c2) +
                        a2 * (b0 * c1 - b1 * c0);
      acc[j] += (double)fabsf(det);
    }
  }
  /* reduce over tri-sub lanes (bits 3..5) — fixed order, deterministic */
  #pragma unroll
  for (int j = 0; j < 8; ++j) {
    acc[j] += __shfl_xor(acc[j], 8, 64);
    acc[j] += __shfl_xor(acc[j], 16, 64);
    acc[j] += __shfl_xor(acc[j], 32, 64);
  }
  if (sub == 0) {
    #pragma unroll
    for (int j = 0; j < 8; ++j) red[ty][boct * 8 + j] = acc[j];
  }
  __syncthreads();
  /* wave 0: cross-wave sum (fixed order); partials[b][blk] for contig read */
  if (ty == 0) {
    const double s = ((red[0][tx] + red[1][tx]) + (red[2][tx] + red[3][tx]));
    partials[(size_t)tx * GBLOCKS + blockIdx.x] = s;
  }
}

/* ---- pass 3: fused finalize + normalize ----
   Each of the 16 blocks per batch redundantly sums that batch's 2048 block
   partials in IDENTICAL fixed order -> bitwise-same scale; then scales its
   float4 chunk. */
__global__ __launch_bounds__(256) void normfin_kernel(
    const float* __restrict__ x, const double* __restrict__ partials,
    float* __restrict__ out) {
  const int batch = blockIdx.x >> 4;
  const int chunk = blockIdx.x & (NCHUNK - 1);
  const int tid = threadIdx.x;
  const int tx = tid & 63;
  const int ty = tid >> 6;
  __shared__ double red[4];

  const double* __restrict__ pb = partials + (size_t)batch * GBLOCKS;
  double local = 0.0;
  #pragma unroll
  for (int k = 0; k < GBLOCKS / 256; ++k) local += pb[tid + k * 256];
  #pragma unroll
  for (int off = 32; off > 0; off >>= 1) local += __shfl_down(local, off, 64);
  if (tx == 0) red[ty] = local;
  __syncthreads();
  const double vol = ((red[0] + red[1]) + (red[2] + red[3])) / 6.0;
  const float s = (float)(1.0 / cbrt(vol));

  const f32x4* __restrict__ xb = (const f32x4*)(x + (size_t)batch * FPB);
  f32x4* __restrict__ ob = (f32x4*)(out + (size_t)batch * FPB);
  const int i1 = min((chunk + 1) * CHUNK, N4);
  for (int i = chunk * CHUNK + tid; i < i1; i += 256) {
    f32x4 v = xb[i];
    v *= s;
    __builtin_nontemporal_store(v, &ob[i]);  /* out never re-read */
  }
}

/* ---------------- fallback (small ws): round-2 XCD-local path ------------ */

#define XCDS 8
#define SLOTS 256
#define BATCH_PER_XCD (NBATCH / XCDS)

__global__ __launch_bounds__(256) void vol_partial_kernel(
    const float* __restrict__ x, const int* __restrict__ M,
    double* __restrict__ partials) {
  const int L = blockIdx.x;
  const int xcd = L & (XCDS - 1);
  const int slot = L >> 3;
  __shared__ double lds[4];
  const int lane = threadIdx.x & 63;
  const int wave = threadIdx.x >> 6;
  for (int bi = 0; bi < BATCH_PER_XCD; ++bi) {
    const int b = xcd * BATCH_PER_XCD + bi;
    const float* __restrict__ xv = x + (size_t)b * FPB;
    double acc = 0.0;
    for (int t = slot * 256 + threadIdx.x; t < NT; t += SLOTS * 256) {
      const int i0 = M[3 * t + 0], i1 = M[3 * t + 1], i2 = M[3 * t + 2];
      const float a0 = xv[3 * i0], a1 = xv[3 * i0 + 1], a2 = xv[3 * i0 + 2];
      const float b0 = xv[3 * i1], b1 = xv[3 * i1 + 1], b2 = xv[3 * i1 + 2];
      const float c0 = xv[3 * i2], c1 = xv[3 * i2 + 1], c2 = xv[3 * i2 + 2];
      const float det = a0 * (b1 * c2 - b2 * c1) + a1 * (b2 * c0 - b0 * c2) +
                        a2 * (b0 * c1 - b1 * c0);
      acc += (double)fabsf(det);
    }
    #pragma unroll
    for (int off = 32; off > 0; off >>= 1) acc += __shfl_down(acc, off, 64);
    if (lane == 0) lds[wave] = acc;
    __syncthreads();
    if (threadIdx.x == 0)
      partials[(size_t)b * SLOTS + slot] = (lds[0] + lds[1]) + (lds[2] + lds[3]);
    __syncthreads();
  }
}

__global__ __launch_bounds__(256) void finalize_kernel(
    const double* __restrict__ partials, float* __restrict__ inv_scale) {
  const int b = blockIdx.x;
  double v = partials[(size_t)b * SLOTS + threadIdx.x];
  #pragma unroll
  for (int off = 32; off > 0; off >>= 1) v += __shfl_down(v, off, 64);
  __shared__ double lds[4];
  const int lane = threadIdx.x & 63;
  const int wave = threadIdx.x >> 6;
  if (lane == 0) lds[wave] = v;
  __syncthreads();
  if (threadIdx.x == 0) {
    const double vol = ((lds[0] + lds[1]) + (lds[2] + lds[3])) / 6.0;
    inv_scale[b] = (float)(1.0 / cbrt(vol));
  }
}

__global__ __launch_bounds__(256) void normalize_kernel(
    const float* __restrict__ x, const float* __restrict__ inv_scale,
    float* __restrict__ out) {
  const int b = blockIdx.y;
  const float s = inv_scale[b];
  const f32x4* __restrict__ xin =
      reinterpret_cast<const f32x4*>(x + (size_t)b * FPB);
  f32x4* __restrict__ o = reinterpret_cast<f32x4*>(out + (size_t)b * FPB);
  const int stride = blockDim.x * gridDim.x;
  for (int i = blockIdx.x * blockDim.x + threadIdx.x; i < N4; i += stride) {
    f32x4 v = xin[i];
    v *= s;
    __builtin_nontemporal_store(v, &o[i]);
  }
}

extern "C" void kernel_launch(void* const* d_in, const int* in_sizes, int n_in,
                              void* d_out, int out_size, void* d_ws, size_t ws_size,
                              hipStream_t stream) {
  const float* x = (const float*)d_in[0];
  const int* M = (const int*)d_in[1];
  float* out = (float*)d_out;

  if (ws_size >= WS_NEED) {
    __half* xH = (__half*)d_ws;
    double* partials = (double*)((char*)d_ws + XH_BYTES);
    transpose_kernel<<<NTILES, 256, 0, stream>>>(x, xH);
    gather_det8_kernel<<<GBLOCKS, 256, 0, stream>>>(xH, M, partials);
    normfin_kernel<<<NBATCH * NCHUNK, 256, 0, stream>>>(x, partials, out);
  } else {
    double* partials = (double*)d_ws;
    float* inv_scale = (float*)(partials + NBATCH * SLOTS);
    vol_partial_kernel<<<XCDS * SLOTS, 256, 0, stream>>>(x, M, partials);
    finalize_kernel<<<NBATCH, SLOTS, 0, stream>>>(partials, inv_scale);
    dim3 gridC(32, NBATCH);
    normalize_kernel<<<gridC, 256, 0, stream>>>(x, inv_scale, out);
  }
}

// Round 12
// 52.418 us; speedup vs baseline: 1.0781x; 1.0188x over previous
//
#include <hip/hip_runtime.h>
#include <hip/hip_fp16.h>

#define NBATCH 64
#define NV 50000
#define NT 100000
#define FPB (NV * 3)          /* floats per batch = 150000 */
#define N4 (FPB / 4)          /* 37500 float4 per batch */

#define NTILES ((FPB + 63) / 64)   /* 2344 transpose tiles */
#define GBLOCKS 3125               /* gather blocks: 12500 waves = NGROUP */
#define NGROUP (NT / 8)            /* 12500 groups of 8 triangles */
#define PROW 3200                  /* padded partials row (floats) */
#define NCHUNK 16                  /* normalize blocks per batch */
#define CHUNK ((N4 + NCHUNK - 1) / NCHUNK)   /* 2344 float4 */

#define XH_HALVES ((size_t)FPB * NBATCH)     /* 9.6e6 halves = 19.2 MB */
#define XH_BYTES (XH_HALVES * 2)
#define WS_NEED (XH_BYTES + (size_t)NBATCH * PROW * 4 + 256)

typedef float f32x4 __attribute__((ext_vector_type(4)));
typedef int i32x4 __attribute__((ext_vector_type(4)));

__device__ __forceinline__ float hext(const i32x4& v, int j) {
  const int word = v[j >> 1];
  const __half2 h = __builtin_bit_cast(__half2, word);
  return (j & 1) ? __high2float(h) : __low2float(h);
}

/* ---- pass 1: x[b][f] -> fp16 planes xH[c][v][b]; (c,v) row = one 128B line.
   Write: lane packs 2 batches as __half2; 2 f-rows per wave-instr. */
__global__ __launch_bounds__(256) void transpose_kernel(
    const float* __restrict__ x, __half* __restrict__ xH) {
  __shared__ float tile[64][65];
  const int tx = threadIdx.x & 63;
  const int ty = threadIdx.x >> 6;
  const int f0 = blockIdx.x * 64;
  const int fl = f0 + tx;
  #pragma unroll
  for (int i = ty; i < 64; i += 4)
    if (fl < FPB) tile[i][tx] = x[(size_t)i * FPB + fl];
  __syncthreads();
  const int hi = (threadIdx.x >> 5) & 1;
  const int j = threadIdx.x & 31;
  #pragma unroll
  for (int it = ty; it < 32; it += 4) {
    const int f = f0 + 2 * it + hi;
    if (f < FPB) {
      const int v = f / 3, c = f - 3 * v;
      const __half2 h2 = __halves2half2(__float2half(tile[2 * j][2 * it + hi]),
                                        __float2half(tile[2 * j + 1][2 * it + hi]));
      *reinterpret_cast<__half2*>(xH + ((size_t)c * NV + v) * 64 + 2 * j) = h2;
    }
  }
}

/* ---- pass 2: 8-triangle packed gather; ONE group per wave (perfect balance,
   HW block-level self-scheduling). lane = (tri_sub = lane>>3, boct = lane&7);
   one dwordx4 wave-load = 8 full 128B rows. Block LDS-reduces 4 waves. ---- */
__global__ __launch_bounds__(256) void gather_det8_kernel(
    const __half* __restrict__ xH, const int* __restrict__ M,
    float* __restrict__ partials) {
  const int ty = threadIdx.x >> 6;
  const int tx = threadIdx.x & 63;
  const int g = blockIdx.x * 4 + ty;      /* group id, < 12500 exactly */
  const int sub = tx >> 3;
  const int boct = tx & 7;
  const __half* __restrict__ pX = xH;
  const __half* __restrict__ pY = xH + (size_t)NV * 64;
  const __half* __restrict__ pZ = xH + (size_t)2 * NV * 64;
  const size_t o = 8 * boct;
  __shared__ float red[4][64];

  const int t = g * 8 + sub;
  const int i0 = M[3 * t + 0];
  const int i1 = M[3 * t + 1];
  const int i2 = M[3 * t + 2];
  const i32x4 A0 = *(const i32x4*)(pX + (size_t)i0 * 64 + o);
  const i32x4 A1 = *(const i32x4*)(pY + (size_t)i0 * 64 + o);
  const i32x4 A2 = *(const i32x4*)(pZ + (size_t)i0 * 64 + o);
  const i32x4 B0 = *(const i32x4*)(pX + (size_t)i1 * 64 + o);
  const i32x4 B1 = *(const i32x4*)(pY + (size_t)i1 * 64 + o);
  const i32x4 B2 = *(const i32x4*)(pZ + (size_t)i1 * 64 + o);
  const i32x4 C0 = *(const i32x4*)(pX + (size_t)i2 * 64 + o);
  const i32x4 C1 = *(const i32x4*)(pY + (size_t)i2 * 64 + o);
  const i32x4 C2 = *(const i32x4*)(pZ + (size_t)i2 * 64 + o);

  float acc[8];
  #pragma unroll
  for (int j = 0; j < 8; ++j) {
    const float a0 = hext(A0, j), a1 = hext(A1, j), a2 = hext(A2, j);
    const float b0 = hext(B0, j), b1 = hext(B1, j), b2 = hext(B2, j);
    const float c0 = hext(C0, j), c1 = hext(C1, j), c2 = hext(C2, j);
    const float det = a0 * (b1 * c2 - b2 * c1) +
                      a1 * (b2 * c0 - b0 * c2) +
                      a2 * (b0 * c1 - b1 * c0);
    acc[j] = fabsf(det);
  }
  /* reduce over tri-sub lanes (bits 3..5) — fixed order, deterministic */
  #pragma unroll
  for (int j = 0; j < 8; ++j) {
    acc[j] += __shfl_xor(acc[j], 8, 64);
    acc[j] += __shfl_xor(acc[j], 16, 64);
    acc[j] += __shfl_xor(acc[j], 32, 64);
  }
  if (sub == 0) {
    #pragma unroll
    for (int j = 0; j < 8; ++j) red[ty][boct * 8 + j] = acc[j];
  }
  __syncthreads();
  /* wave 0: cross-wave sum (fixed order); partials[b][blk] for contig read */
  if (ty == 0) {
    const float s = ((red[0][tx] + red[1][tx]) + (red[2][tx] + red[3][tx]));
    partials[(size_t)tx * PROW + blockIdx.x] = s;
  }
}

/* ---- pass 3: fused finalize + normalize. Each of the 16 blocks per batch
   redundantly sums the batch's 3125 block-partials in IDENTICAL fixed order
   (double accum) -> bitwise-same scale; then scales its float4 chunk. ---- */
__global__ __launch_bounds__(256) void normfin_kernel(
    const float* __restrict__ x, const float* __restrict__ partials,
    float* __restrict__ out) {
  const int batch = blockIdx.x >> 4;
  const int chunk = blockIdx.x & (NCHUNK - 1);
  const int tid = threadIdx.x;
  const int tx = tid & 63;
  const int ty = tid >> 6;
  __shared__ double red[4];

  const float* __restrict__ pb = partials + (size_t)batch * PROW;
  double local = 0.0;
  #pragma unroll
  for (int k = 0; k < (PROW + 255) / 256; ++k) {
    const int idx = tid + k * 256;
    if (idx < GBLOCKS) local += (double)pb[idx];
  }
  #pragma unroll
  for (int off = 32; off > 0; off >>= 1) local += __shfl_down(local, off, 64);
  if (tx == 0) red[ty] = local;
  __syncthreads();
  const double vol = ((red[0] + red[1]) + (red[2] + red[3])) / 6.0;
  const float s = (float)(1.0 / cbrt(vol));

  const f32x4* __restrict__ xb = (const f32x4*)(x + (size_t)batch * FPB);
  f32x4* __restrict__ ob = (f32x4*)(out + (size_t)batch * FPB);
  const int i1 = min((chunk + 1) * CHUNK, N4);
  for (int i = chunk * CHUNK + tid; i < i1; i += 256) {
    f32x4 v = xb[i];
    v *= s;
    __builtin_nontemporal_store(v, &ob[i]);  /* out never re-read */
  }
}

/* ---------------- fallback (small ws): round-2 XCD-local path ------------ */

#define XCDS 8
#define SLOTS 256
#define BATCH_PER_XCD (NBATCH / XCDS)

__global__ __launch_bounds__(256) void vol_partial_kernel(
    const float* __restrict__ x, const int* __restrict__ M,
    double* __restrict__ partials) {
  const int L = blockIdx.x;
  const int xcd = L & (XCDS - 1);
  const int slot = L >> 3;
  __shared__ double lds[4];
  const int lane = threadIdx.x & 63;
  const int wave = threadIdx.x >> 6;
  for (int bi = 0; bi < BATCH_PER_XCD; ++bi) {
    const int b = xcd * BATCH_PER_XCD + bi;
    const float* __restrict__ xv = x + (size_t)b * FPB;
    double acc = 0.0;
    for (int t = slot * 256 + threadIdx.x; t < NT; t += SLOTS * 256) {
      const int i0 = M[3 * t + 0], i1 = M[3 * t + 1], i2 = M[3 * t + 2];
      const float a0 = xv[3 * i0], a1 = xv[3 * i0 + 1], a2 = xv[3 * i0 + 2];
      const float b0 = xv[3 * i1], b1 = xv[3 * i1 + 1], b2 = xv[3 * i1 + 2];
      const float c0 = xv[3 * i2], c1 = xv[3 * i2 + 1], c2 = xv[3 * i2 + 2];
      const float det = a0 * (b1 * c2 - b2 * c1) + a1 * (b2 * c0 - b0 * c2) +
                        a2 * (b0 * c1 - b1 * c0);
      acc += (double)fabsf(det);
    }
    #pragma unroll
    for (int off = 32; off > 0; off >>= 1) acc += __shfl_down(acc, off, 64);
    if (lane == 0) lds[wave] = acc;
    __syncthreads();
    if (threadIdx.x == 0)
      partials[(size_t)b * SLOTS + slot] = (lds[0] + lds[1]) + (lds[2] + lds[3]);
    __syncthreads();
  }
}

__global__ __launch_bounds__(256) void finalize_kernel(
    const double* __restrict__ partials, float* __restrict__ inv_scale) {
  const int b = blockIdx.x;
  double v = partials[(size_t)b * SLOTS + threadIdx.x];
  #pragma unroll
  for (int off = 32; off > 0; off >>= 1) v += __shfl_down(v, off, 64);
  __shared__ double lds[4];
  const int lane = threadIdx.x & 63;
  const int wave = threadIdx.x >> 6;
  if (lane == 0) lds[wave] = v;
  __syncthreads();
  if (threadIdx.x == 0) {
    const double vol = ((lds[0] + lds[1]) + (lds[2] + lds[3])) / 6.0;
    inv_scale[b] = (float)(1.0 / cbrt(vol));
  }
}

__global__ __launch_bounds__(256) void normalize_kernel(
    const float* __restrict__ x, const float* __restrict__ inv_scale,
    float* __restrict__ out) {
  const int b = blockIdx.y;
  const float s = inv_scale[b];
  const f32x4* __restrict__ xin =
      reinterpret_cast<const f32x4*>(x + (size_t)b * FPB);
  f32x4* __restrict__ o = reinterpret_cast<f32x4*>(out + (size_t)b * FPB);
  const int stride = blockDim.x * gridDim.x;
  for (int i = blockIdx.x * blockDim.x + threadIdx.x; i < N4; i += stride) {
    f32x4 v = xin[i];
    v *= s;
    __builtin_nontemporal_store(v, &o[i]);
  }
}

extern "C" void kernel_launch(void* const* d_in, const int* in_sizes, int n_in,
                              void* d_out, int out_size, void* d_ws, size_t ws_size,
                              hipStream_t stream) {
  const float* x = (const float*)d_in[0];
  const int* M = (const int*)d_in[1];
  float* out = (float*)d_out;

  if (ws_size >= WS_NEED) {
    __half* xH = (__half*)d_ws;
    float* partials = (float*)((char*)d_ws + XH_BYTES);
    transpose_kernel<<<NTILES, 256, 0, stream>>>(x, xH);
    gather_det8_kernel<<<GBLOCKS, 256, 0, stream>>>(xH, M, partials);
    normfin_kernel<<<NBATCH * NCHUNK, 256, 0, stream>>>(x, partials, out);
  } else {
    double* partials = (double*)d_ws;
    float* inv_scale = (float*)(partials + NBATCH * SLOTS);
    vol_partial_kernel<<<XCDS * SLOTS, 256, 0, stream>>>(x, M, partials);
    finalize_kernel<<<NBATCH, SLOTS, 0, stream>>>(partials, inv_scale);
    dim3 gridC(32, NBATCH);
    normalize_kernel<<<gridC, 256, 0, stream>>>(x, inv_scale, out);
  }
}